// Round 1
// baseline (414.044 us; speedup 1.0000x reference)
//
#include <hip/hip_runtime.h>
#include <math.h>

#define Mn 4096
#define Dn 64

// ---- workspace offsets (in floats) ----
#define OFF_A2   0
#define OFF_K    4096
#define OFF_Q    8192
#define OFF_H    12288
#define OFF_MUA  16384              /* 4*(Mn+1) = 16388 */
#define OFF_QS   32772
#define OFF_QSD  36868
#define OFF_CRIT 40964              /* Mn+1 = 4097 */
#define SC_PU    45064
#define SC_INVPU 45065
#define SC_NPV   45066
#define SC_PV    45067
#define SC_INVPV 45068
#define SC_DENOM 45069
#define SC_PRUNE 45070              /* int slot */

// ---- output offsets (in floats) ----
#define O_MU   0
#define O_SIG  16384
#define O_Q    16793600
#define O_DICT 33570816
#define O_TI   33832960
#define O_NNUM 33837056
#define O_NDEN 33837060

__device__ __forceinline__ float waveReduceSum(float v) {
#pragma unroll
    for (int o = 32; o > 0; o >>= 1) v += __shfl_down(v, o);
    return v;
}

// K1: a2[i] = |d_i|^2 ; k[i] = exp(-max(|d_i|^2+|x|^2-2 d_i.x,0)/128) * alloc_i
__global__ void k1_prep(const float* __restrict__ dict, const float* __restrict__ x,
                        const float* __restrict__ ti, float* __restrict__ ws) {
    int row  = blockIdx.x * 4 + (threadIdx.x >> 6);
    int lane = threadIdx.x & 63;
    float d  = dict[row * Dn + lane];
    float xv = x[lane];
    float a2 = waveReduceSum(d * d);
    float x2 = waveReduceSum(xv * xv);
    float dx = waveReduceSum(d * xv);
    if (lane == 0) {
        ws[OFF_A2 + row] = a2;
        float d2 = fmaxf(a2 + x2 - 2.0f * dx, 0.0f);
        float kv = expf(d2 * (-1.0f / 128.0f));
        ws[OFF_K + row] = (ti[row] >= 0.0f) ? kv : 0.0f;
    }
}

// K2: q = Q @ k ; also zero h
__global__ void k2_q(const float* __restrict__ Q, float* __restrict__ ws) {
    __shared__ float red[4];
    const int row = blockIdx.x;
    const int tid = threadIdx.x;
    const float* k  = ws + OFF_K;
    const float* Qr = Q + (size_t)row * Mn;
    float s = 0.0f;
    for (int j = tid; j < Mn; j += 256) s += Qr[j] * k[j];
    s = waveReduceSum(s);
    if ((tid & 63) == 0) red[tid >> 6] = s;
    __syncthreads();
    if (tid == 0) {
        ws[OFF_Q + row] = red[0] + red[1] + red[2] + red[3];
        ws[OFF_H + row] = 0.0f;
    }
}

// K3: sig = 0.999*sigma + 0.001*Kdd(masked)  (stored into out sig region)
//     h += sig @ q   (atomic partial per 256-col chunk)
__global__ __launch_bounds__(256) void k3_sig_h(
        const float* __restrict__ dict, const float* __restrict__ sigma,
        const float* __restrict__ ti, float* __restrict__ ws, float* __restrict__ out) {
    __shared__ float As[64 * 65];
    __shared__ float Bs[64 * 65];
    __shared__ float hred[64 * 16];
    const int tid = threadIdx.x;
    const int tx = tid & 15, ty = tid >> 4;
    const int r0 = blockIdx.y * 64;
    const int cchunk = blockIdx.x * 256;

    for (int l = 0; l < 16; ++l) {
        int lin = tid + l * 256;
        int row = lin >> 6, col = lin & 63;
        As[row * 65 + col] = dict[(size_t)(r0 + row) * Dn + col];
    }

    float a2i[4], ali[4];
#pragma unroll
    for (int r = 0; r < 4; ++r) {
        int gi = r0 + ty * 4 + r;
        a2i[r] = ws[OFF_A2 + gi];
        ali[r] = (ti[gi] >= 0.0f) ? 1.0f : 0.0f;
    }

    float hacc[4] = {0.f, 0.f, 0.f, 0.f};

    for (int ct = 0; ct < 4; ++ct) {
        const int c0 = cchunk + ct * 64;
        __syncthreads();
        for (int l = 0; l < 16; ++l) {
            int lin = tid + l * 256;
            int row = lin >> 6, col = lin & 63;
            Bs[row * 65 + col] = dict[(size_t)(c0 + row) * Dn + col];
        }
        __syncthreads();

        float acc[4][4];
#pragma unroll
        for (int r = 0; r < 4; ++r)
#pragma unroll
            for (int c = 0; c < 4; ++c) acc[r][c] = 0.0f;

#pragma unroll 8
        for (int kk = 0; kk < 64; ++kk) {
            float a[4], b[4];
#pragma unroll
            for (int r = 0; r < 4; ++r) a[r] = As[(ty * 4 + r) * 65 + kk];
#pragma unroll
            for (int c = 0; c < 4; ++c) b[c] = Bs[(tx * 4 + c) * 65 + kk];
#pragma unroll
            for (int r = 0; r < 4; ++r)
#pragma unroll
                for (int c = 0; c < 4; ++c) acc[r][c] = fmaf(a[r], b[c], acc[r][c]);
        }

        const int j = c0 + tx * 4;
        const float4 a2j4 = *(const float4*)(ws + OFF_A2 + j);
        const float4 qj4  = *(const float4*)(ws + OFF_Q + j);
        const float4 tj4  = *(const float4*)(ti + j);
        float a2j[4] = {a2j4.x, a2j4.y, a2j4.z, a2j4.w};
        float qj[4]  = {qj4.x, qj4.y, qj4.z, qj4.w};
        float alj[4] = {tj4.x >= 0.f ? 1.f : 0.f, tj4.y >= 0.f ? 1.f : 0.f,
                        tj4.z >= 0.f ? 1.f : 0.f, tj4.w >= 0.f ? 1.f : 0.f};

#pragma unroll
        for (int r = 0; r < 4; ++r) {
            const int gi = r0 + ty * 4 + r;
            const size_t off = (size_t)gi * Mn + j;
            const float4 sg = *(const float4*)(sigma + off);
            float sv[4] = {sg.x, sg.y, sg.z, sg.w};
            float res[4];
#pragma unroll
            for (int c = 0; c < 4; ++c) {
                float d2 = fmaxf(a2i[r] + a2j[c] - 2.0f * acc[r][c], 0.0f);
                float kv = __expf(d2 * (-1.0f / 128.0f)) * ali[r] * alj[c];
                res[c] = 0.999f * sv[c] + 0.001f * kv;
                hacc[r] += res[c] * qj[c];
            }
            float4 o = {res[0], res[1], res[2], res[3]};
            *(float4*)(out + O_SIG + off) = o;
        }
    }

    __syncthreads();
#pragma unroll
    for (int r = 0; r < 4; ++r) hred[(ty * 4 + r) * 16 + tx] = hacc[r];
    __syncthreads();
    if (tid < 64) {
        float s = 0.0f;
#pragma unroll
        for (int c = 0; c < 16; ++c) s += hred[tid * 16 + c];
        atomicAdd(ws + OFF_H + r0 + tid, s);
    }
}

__device__ __forceinline__ float blockReduce1024(float v, float* sred) {
    v = waveReduceSum(v);
    int tid = threadIdx.x;
    __syncthreads();
    if ((tid & 63) == 0) sred[tid >> 6] = v;
    __syncthreads();
    float r = 0.0f;
    if (tid == 0) {
#pragma unroll
        for (int i = 0; i < 16; ++i) r += sred[i];
    }
    return r;
}

// K4: scalars pu/npv/pv, pred_mean, nnum/nden, mu_a
__global__ __launch_bounds__(1024) void k4_scalars(
        const float* __restrict__ mu, const float* __restrict__ y,
        const float* __restrict__ nn, const float* __restrict__ nd,
        float* __restrict__ ws, float* __restrict__ out) {
    __shared__ float sred[16];
    __shared__ float sb[8];
    const int tid = threadIdx.x;
    const float* k = ws + OFF_K;
    const float* q = ws + OFF_Q;
    const float* h = ws + OFF_H;
    float kq = 0, qh = 0, p0 = 0, p1 = 0, p2 = 0, p3 = 0;
    for (int i = tid; i < Mn; i += 1024) {
        float qi = q[i];
        kq += k[i] * qi;
        qh += qi * h[i];
        p0 += qi * mu[0 * Mn + i];
        p1 += qi * mu[1 * Mn + i];
        p2 += qi * mu[2 * Mn + i];
        p3 += qi * mu[3 * Mn + i];
    }
    float rkq = blockReduce1024(kq, sred);
    float rqh = blockReduce1024(qh, sred);
    float r0 = blockReduce1024(p0, sred);
    float r1 = blockReduce1024(p1, sred);
    float r2 = blockReduce1024(p2, sred);
    float r3 = blockReduce1024(p3, sred);
    if (tid == 0) {
        const float sf = sqrtf(0.999f);
        float pu  = fmaxf(1.0f - rkq, 0.0f);      // K_xx = 1 + 1e-10 == 1.0f in fp32
        float npv = fmaxf(pu + rqh, 0.0f);
        float pv  = 0.01f + npv;
        ws[SC_PU] = pu;
        ws[SC_INVPU] = 1.0f / pu;
        ws[SC_NPV] = npv;
        ws[SC_PV] = pv;
        ws[SC_INVPV] = 1.0f / pv;
        float pm[4] = {sf * r0, sf * r1, sf * r2, sf * r3};
#pragma unroll
        for (int yd = 0; yd < 4; ++yd) {
            float yv = y[yd];
            float dy = yv - pm[yd];
            float dl = dy / pv;
            sb[yd] = dl;
            ws[OFF_MUA + yd * (Mn + 1) + Mn] = pm[yd] + dl * npv;
            out[O_NNUM + yd] = nn[yd] + 0.999f * (dy * dy) / pv;
        }
        out[O_NDEN] = nd[0] + 0.999f;
    }
    __syncthreads();
    const float sf = sqrtf(0.999f);
    float d0 = sb[0], d1 = sb[1], d2 = sb[2], d3 = sb[3];
    for (int i = tid; i < Mn; i += 1024) {
        float hi = h[i];
        ws[OFF_MUA + 0 * (Mn + 1) + i] = sf * mu[0 * Mn + i] + d0 * hi;
        ws[OFF_MUA + 1 * (Mn + 1) + i] = sf * mu[1 * Mn + i] + d1 * hi;
        ws[OFF_MUA + 2 * (Mn + 1) + i] = sf * mu[2 * Mn + i] + d2 * hi;
        ws[OFF_MUA + 3 * (Mn + 1) + i] = sf * mu[3 * Mn + i] + d3 * hi;
    }
}

// K5: criterion rows (one wave per row, j = 0..Mn inclusive)
__global__ void k5_crit(const float* __restrict__ Q, const float* __restrict__ ti,
                        float* __restrict__ ws) {
    const int row  = blockIdx.x * 4 + (threadIdx.x >> 6);
    const int lane = threadIdx.x & 63;
    if (row > Mn) return;
    const float pu = ws[SC_PU];
    if (pu < 1e-10f) {
        if (lane == 0) ws[OFF_CRIT + row] = (row < Mn) ? 1.0f : 0.0f;
        return;
    }
    const float inv_pu = ws[SC_INVPU];
    const float* q = ws + OFF_Q;
    const float* mua = ws + OFF_MUA;
    const float p2i = (row < Mn) ? q[row] : -1.0f;
    const float* Qrow = Q + (size_t)row * Mn;  // only dereferenced when row < Mn
    float n0 = 0, n1 = 0, n2 = 0, n3 = 0;
    const bool rin = (row < Mn);
    for (int j = lane; j <= Mn; j += 64) {
        float p2j = (j < Mn) ? q[j] : -1.0f;
        float qa = p2i * p2j * inv_pu;
        if (rin && j < Mn) qa += Qrow[j];
        n0 += qa * mua[0 * (Mn + 1) + j];
        n1 += qa * mua[1 * (Mn + 1) + j];
        n2 += qa * mua[2 * (Mn + 1) + j];
        n3 += qa * mua[3 * (Mn + 1) + j];
    }
    n0 = waveReduceSum(n0);
    n1 = waveReduceSum(n1);
    n2 = waveReduceSum(n2);
    n3 = waveReduceSum(n3);
    if (lane == 0) {
        bool xa = (row == Mn) ? true : (ti[row] >= 0.0f);
        float crit = 0.0f;
        if (xa) {
            float dq = p2i * p2i * inv_pu + (rin ? Qrow[row] : 0.0f);
            crit = fabsf(n0 / dq) + fabsf(n1 / dq) + fabsf(n2 / dq) + fabsf(n3 / dq);
        }
        ws[OFF_CRIT + row] = crit;
    }
}

// K6: argmin (first occurrence) -> prune, denom
__global__ __launch_bounds__(1024) void k6_argmin(const float* __restrict__ Q,
                                                  const float* __restrict__ ti,
                                                  float* __restrict__ ws) {
    __shared__ float sval[1024];
    __shared__ int   sidx[1024];
    const int tid = threadIdx.x;
    float bv = INFINITY;
    int bi = Mn + 1;
    for (int i = tid; i <= Mn; i += 1024) {
        float v = ws[OFF_CRIT + i];
        if (v < bv) { bv = v; bi = i; }
    }
    sval[tid] = bv; sidx[tid] = bi;
    __syncthreads();
    for (int s = 512; s > 0; s >>= 1) {
        if (tid < s) {
            float ov = sval[tid + s]; int oi = sidx[tid + s];
            if (ov < sval[tid] || (ov == sval[tid] && oi < sidx[tid])) {
                sval[tid] = ov; sidx[tid] = oi;
            }
        }
        __syncthreads();
    }
    if (tid == 0) {
        int prune = sidx[0];
        ((int*)ws)[SC_PRUNE] = prune;
        float inv_pu = ws[SC_INVPU];
        bool xa = (prune == Mn) ? true : (ti[prune] >= 0.0f);
        float qap;
        if (prune < Mn) {
            float qp = ws[OFF_Q + prune];
            qap = Q[(size_t)prune * Mn + prune] + qp * qp * inv_pu;
        } else {
            qap = inv_pu;  // Q_a[M,M] = (-1)(-1)/pu
        }
        ws[SC_DENOM] = xa ? qap : INFINITY;
    }
}

// K6b: dict_n, ti_n, Qs, Qsd
__global__ void k6b_vec(const float* __restrict__ Q, const float* __restrict__ dict,
                        const float* __restrict__ x, const float* __restrict__ ti,
                        const int* __restrict__ tptr, float* __restrict__ ws,
                        float* __restrict__ out) {
    const int tid = blockIdx.x * 256 + threadIdx.x;
    const int prune = ((const int*)ws)[SC_PRUNE];
    const int row = tid >> 6, col = tid & 63;
    out[O_DICT + tid] = (row == prune) ? x[col] : dict[tid];
    if (tid < Mn) {
        float tv = ti[tid];
        if (tid == prune) {
            int raw = *tptr;  // hedge: accept either int32 or float32-encoded t
            tv = (raw >= 0 && raw < (1 << 30)) ? (float)raw : __int_as_float(raw);
        }
        out[O_TI + tid] = tv;
        const float inv_pu = ws[SC_INVPU];
        const float denom  = ws[SC_DENOM];
        const float p2p = (prune < Mn) ? ws[OFF_Q + prune] : -1.0f;
        float qs;
        if (tid == prune) {
            qs = -p2p * inv_pu;  // Q_a[M, prune]
        } else {
            float base = (prune < Mn) ? Q[(size_t)tid * Mn + prune] : 0.0f;
            qs = base + ws[OFF_Q + tid] * p2p * inv_pu;
        }
        ws[OFF_QS + tid] = qs;
        ws[OFF_QSD + tid] = qs / denom;
    }
}

// K7: Q_n rewrite
__global__ void k7_qn(const float* __restrict__ Q, float* __restrict__ out,
                      const float* __restrict__ ws) {
    const int i = blockIdx.x;
    const int prune = ((const int*)ws)[SC_PRUNE];
    const float inv_pu = ws[SC_INVPU];
    const float* q = ws + OFF_Q;
    const int pi = (i == prune) ? Mn : i;
    const bool piok = (pi < Mn);
    const float p2i = piok ? q[pi] : -1.0f;
    const float qsi = ws[OFF_QS + i];
    const float* Qrow = Q + (size_t)pi * Mn;  // only dereferenced when piok
    float* orow = out + O_Q + (size_t)i * Mn;
    for (int j = threadIdx.x; j < Mn; j += 256) {
        float p2j = (j == prune) ? -1.0f : q[j];
        float base = (piok && j != prune) ? Qrow[j] : 0.0f;
        float qa = base + p2i * p2j * inv_pu;
        orow[j] = qa - qsi * ws[OFF_QSD + j];
    }
}

// K8: sig_n rewrite (in-place over the sig staged in out)
__global__ void k8_sign(float* __restrict__ out, const float* __restrict__ ws) {
    const int i = blockIdx.x;
    const int prune = ((const int*)ws)[SC_PRUNE];
    const float inv_pv = ws[SC_INVPV];
    const float npv = ws[SC_NPV];
    const float* h = ws + OFF_H;
    const bool ip = (i == prune);
    const float ai = (out[O_TI + i] >= 0.0f) ? 1.0f : 0.0f;
    const float p_i = ip ? npv : h[i];
    const float hi = h[i];
    float* srow = out + O_SIG + (size_t)i * Mn;
    for (int j = threadIdx.x; j < Mn; j += 256) {
        const bool jp = (j == prune);
        float p_j = jp ? npv : h[j];
        float base;
        if (!ip && !jp) base = srow[j];
        else if (ip && jp) base = npv;
        else if (ip) base = h[j];
        else base = hi;
        float aj = (out[O_TI + j] >= 0.0f) ? 1.0f : 0.0f;
        srow[j] = ai * aj * (base - p_i * p_j * inv_pv);
    }
}

// K9: mu_n
__global__ void k9_mun(float* __restrict__ out, const float* __restrict__ ws) {
    const int idx = blockIdx.x * 256 + threadIdx.x;
    const int prune = ((const int*)ws)[SC_PRUNE];
    const int yd = idx >> 12;       // /4096
    const int i  = idx & (Mn - 1);
    float tin = out[O_TI + i];
    float v;
    if (tin < 0.0f) v = 0.0f;
    else v = ws[OFF_MUA + yd * (Mn + 1) + ((i == prune) ? Mn : i)];
    out[O_MU + idx] = v;
}

extern "C" void kernel_launch(void* const* d_in, const int* in_sizes, int n_in,
                              void* d_out, int out_size, void* d_ws, size_t ws_size,
                              hipStream_t stream) {
    const float* dict  = (const float*)d_in[0];
    const float* mu    = (const float*)d_in[1];
    const float* sigma = (const float*)d_in[2];
    const float* Q     = (const float*)d_in[3];
    const float* x     = (const float*)d_in[4];
    const float* y     = (const float*)d_in[5];
    const float* nn    = (const float*)d_in[6];
    const float* nd    = (const float*)d_in[7];
    const float* ti    = (const float*)d_in[8];
    const int*   tptr  = (const int*)d_in[9];
    float* out = (float*)d_out;
    float* ws  = (float*)d_ws;

    k1_prep<<<1024, 256, 0, stream>>>(dict, x, ti, ws);
    k2_q<<<4096, 256, 0, stream>>>(Q, ws);
    k3_sig_h<<<dim3(16, 64), 256, 0, stream>>>(dict, sigma, ti, ws, out);
    k4_scalars<<<1, 1024, 0, stream>>>(mu, y, nn, nd, ws, out);
    k5_crit<<<1025, 256, 0, stream>>>(Q, ti, ws);
    k6_argmin<<<1, 1024, 0, stream>>>(Q, ti, ws);
    k6b_vec<<<1024, 256, 0, stream>>>(Q, dict, x, ti, tptr, ws, out);
    k7_qn<<<4096, 256, 0, stream>>>(Q, out, ws);
    k8_sign<<<4096, 256, 0, stream>>>(out, ws);
    k9_mun<<<64, 256, 0, stream>>>(out, ws);
}

// Round 2
// 345.217 us; speedup vs baseline: 1.1994x; 1.1994x over previous
//
#include <hip/hip_runtime.h>
#include <math.h>

#define Mn 4096
#define Dn 64
#define MUA_STRIDE 4104

// ---- workspace offsets (in floats) ----
// A2/K are dead after k4; CRIT (k5..k6) overlaps them.
#define OFF_A2   0                  /* k1..k3 */
#define OFF_CRIT 0                  /* k5..k6, 4097 floats (overlaps A2 + K[0]) */
#define OFF_K    4096               /* k1..k4 */
#define OFF_Q    8192
#define OFF_H    12288
#define OFF_MUA  16384              /* 4 x MUA_STRIDE = 16416 */
#define OFF_QS   32800
#define OFF_QSD  36896
#define SC_PU    40992
#define SC_INVPU 40993
#define SC_NPV   40994
#define SC_PV    40995
#define SC_INVPV 40996
#define SC_DENOM 40997
#define SC_PRUNE 40998              /* int slot */

// ---- output offsets (in floats) ----
#define O_MU   0
#define O_SIG  16384
#define O_Q    16793600
#define O_DICT 33570816
#define O_TI   33832960
#define O_NNUM 33837056
#define O_NDEN 33837060

__device__ __forceinline__ float waveReduceSum(float v) {
#pragma unroll
    for (int o = 32; o > 0; o >>= 1) v += __shfl_down(v, o);
    return v;
}

// K1: a2[i] = |d_i|^2 ; k[i] = exp(-max(|d_i|^2+|x|^2-2 d_i.x,0)/128) * alloc_i
__global__ void k1_prep(const float* __restrict__ dict, const float* __restrict__ x,
                        const float* __restrict__ ti, float* __restrict__ ws) {
    int row  = blockIdx.x * 4 + (threadIdx.x >> 6);
    int lane = threadIdx.x & 63;
    float d  = dict[row * Dn + lane];
    float xv = x[lane];
    float a2 = waveReduceSum(d * d);
    float x2 = waveReduceSum(xv * xv);
    float dx = waveReduceSum(d * xv);
    if (lane == 0) {
        ws[OFF_A2 + row] = a2;
        float d2 = fmaxf(a2 + x2 - 2.0f * dx, 0.0f);
        float kv = expf(d2 * (-1.0f / 128.0f));
        ws[OFF_K + row] = (ti[row] >= 0.0f) ? kv : 0.0f;
    }
}

// K2: q = Q @ k ; also zero h
__global__ void k2_q(const float* __restrict__ Q, float* __restrict__ ws) {
    __shared__ float red[4];
    const int row = blockIdx.x;
    const int tid = threadIdx.x;
    const float4* Qr = (const float4*)(Q + (size_t)row * Mn);
    const float4* kv = (const float4*)(ws + OFF_K);
    float s = 0.0f;
#pragma unroll
    for (int it = 0; it < 4; ++it) {
        int u = tid + it * 256;
        float4 a = Qr[u], b = kv[u];
        s += a.x * b.x + a.y * b.y + a.z * b.z + a.w * b.w;
    }
    s = waveReduceSum(s);
    if ((tid & 63) == 0) red[tid >> 6] = s;
    __syncthreads();
    if (tid == 0) {
        ws[OFF_Q + row] = red[0] + red[1] + red[2] + red[3];
        ws[OFF_H + row] = 0.0f;
    }
}

// K3: sig = 0.999*sigma + 0.001*Kdd(masked)  (stored into out sig region)
//     h += sig @ q   (atomic partial per 256-col chunk)
// K-major transposed LDS tiles: T[kk*68 + row] -> inner loop is 2x ds_read_b128
// + 16 v_fma per K-step (compute-bound); stride 68 keeps 16B alignment and
// spreads banks. Staging uses a permuted map so transpose stores are ~2-way.
__global__ __launch_bounds__(256, 4) void k3_sig_h(
        const float* __restrict__ dict, const float* __restrict__ sigma,
        const float* __restrict__ ti, float* __restrict__ ws, float* __restrict__ out) {
    __shared__ __align__(16) float At[64 * 68];
    __shared__ __align__(16) float Bt[64 * 68];
    __shared__ float hred[64 * 16];
    const int tid = threadIdx.x;
    const int tx = tid & 15, ty = tid >> 4;
    const int r0 = blockIdx.y * 64;
    const int cchunk = blockIdx.x * 256;
    const int pidx = ((tid & 15) << 4) | (tid >> 4);  // permuted float4-unit id

    // stage A (rows r0..r0+63) transposed
#pragma unroll
    for (int l = 0; l < 4; ++l) {
        int u = pidx + l * 256;          // float4 unit 0..1023
        int row = u >> 4;                // 0..63
        int col = (u & 15) << 2;         // 0..60
        float4 v = *(const float4*)(dict + (size_t)(r0 + row) * Dn + col);
        At[(col + 0) * 68 + row] = v.x;
        At[(col + 1) * 68 + row] = v.y;
        At[(col + 2) * 68 + row] = v.z;
        At[(col + 3) * 68 + row] = v.w;
    }

    float a2i[4], ali[4];
#pragma unroll
    for (int r = 0; r < 4; ++r) {
        int gi = r0 + ty * 4 + r;
        a2i[r] = ws[OFF_A2 + gi];
        ali[r] = (ti[gi] >= 0.0f) ? 1.0f : 0.0f;
    }

    float hacc[4] = {0.f, 0.f, 0.f, 0.f};

    for (int ct = 0; ct < 4; ++ct) {
        const int c0 = cchunk + ct * 64;
        __syncthreads();
#pragma unroll
        for (int l = 0; l < 4; ++l) {
            int u = pidx + l * 256;
            int row = u >> 4;
            int col = (u & 15) << 2;
            float4 v = *(const float4*)(dict + (size_t)(c0 + row) * Dn + col);
            Bt[(col + 0) * 68 + row] = v.x;
            Bt[(col + 1) * 68 + row] = v.y;
            Bt[(col + 2) * 68 + row] = v.z;
            Bt[(col + 3) * 68 + row] = v.w;
        }
        __syncthreads();

        float acc[4][4];
#pragma unroll
        for (int r = 0; r < 4; ++r)
#pragma unroll
            for (int c = 0; c < 4; ++c) acc[r][c] = 0.0f;

#pragma unroll
        for (int kk = 0; kk < 64; ++kk) {
            float4 av = *(const float4*)(At + kk * 68 + (ty << 2));
            float4 bv = *(const float4*)(Bt + kk * 68 + (tx << 2));
            acc[0][0] = fmaf(av.x, bv.x, acc[0][0]);
            acc[0][1] = fmaf(av.x, bv.y, acc[0][1]);
            acc[0][2] = fmaf(av.x, bv.z, acc[0][2]);
            acc[0][3] = fmaf(av.x, bv.w, acc[0][3]);
            acc[1][0] = fmaf(av.y, bv.x, acc[1][0]);
            acc[1][1] = fmaf(av.y, bv.y, acc[1][1]);
            acc[1][2] = fmaf(av.y, bv.z, acc[1][2]);
            acc[1][3] = fmaf(av.y, bv.w, acc[1][3]);
            acc[2][0] = fmaf(av.z, bv.x, acc[2][0]);
            acc[2][1] = fmaf(av.z, bv.y, acc[2][1]);
            acc[2][2] = fmaf(av.z, bv.z, acc[2][2]);
            acc[2][3] = fmaf(av.z, bv.w, acc[2][3]);
            acc[3][0] = fmaf(av.w, bv.x, acc[3][0]);
            acc[3][1] = fmaf(av.w, bv.y, acc[3][1]);
            acc[3][2] = fmaf(av.w, bv.z, acc[3][2]);
            acc[3][3] = fmaf(av.w, bv.w, acc[3][3]);
        }

        const int j = c0 + tx * 4;
        const float4 a2j4 = *(const float4*)(ws + OFF_A2 + j);
        const float4 qj4  = *(const float4*)(ws + OFF_Q + j);
        const float4 tj4  = *(const float4*)(ti + j);
        float a2j[4] = {a2j4.x, a2j4.y, a2j4.z, a2j4.w};
        float qj[4]  = {qj4.x, qj4.y, qj4.z, qj4.w};
        float alj[4] = {tj4.x >= 0.f ? 1.f : 0.f, tj4.y >= 0.f ? 1.f : 0.f,
                        tj4.z >= 0.f ? 1.f : 0.f, tj4.w >= 0.f ? 1.f : 0.f};

#pragma unroll
        for (int r = 0; r < 4; ++r) {
            const int gi = r0 + ty * 4 + r;
            const size_t off = (size_t)gi * Mn + j;
            const float4 sg = *(const float4*)(sigma + off);
            float sv[4] = {sg.x, sg.y, sg.z, sg.w};
            float res[4];
#pragma unroll
            for (int c = 0; c < 4; ++c) {
                float d2 = fmaxf(a2i[r] + a2j[c] - 2.0f * acc[r][c], 0.0f);
                float kv = __expf(d2 * (-1.0f / 128.0f)) * ali[r] * alj[c];
                res[c] = 0.999f * sv[c] + 0.001f * kv;
                hacc[r] += res[c] * qj[c];
            }
            float4 o = {res[0], res[1], res[2], res[3]};
            *(float4*)(out + O_SIG + off) = o;
        }
    }

    __syncthreads();
#pragma unroll
    for (int r = 0; r < 4; ++r) hred[(ty * 4 + r) * 16 + tx] = hacc[r];
    __syncthreads();
    if (tid < 64) {
        float s = 0.0f;
#pragma unroll
        for (int c = 0; c < 16; ++c) s += hred[tid * 16 + c];
        atomicAdd(ws + OFF_H + r0 + tid, s);
    }
}

__device__ __forceinline__ float blockReduce1024(float v, float* sred) {
    v = waveReduceSum(v);
    int tid = threadIdx.x;
    __syncthreads();
    if ((tid & 63) == 0) sred[tid >> 6] = v;
    __syncthreads();
    float r = 0.0f;
    if (tid == 0) {
#pragma unroll
        for (int i = 0; i < 16; ++i) r += sred[i];
    }
    return r;
}

// K4: scalars pu/npv/pv, pred_mean, nnum/nden, mu_a
__global__ __launch_bounds__(1024) void k4_scalars(
        const float* __restrict__ mu, const float* __restrict__ y,
        const float* __restrict__ nn, const float* __restrict__ nd,
        float* __restrict__ ws, float* __restrict__ out) {
    __shared__ float sred[16];
    __shared__ float sb[8];
    const int tid = threadIdx.x;
    const float* k = ws + OFF_K;
    const float* q = ws + OFF_Q;
    const float* h = ws + OFF_H;
    float kq = 0, qh = 0, p0 = 0, p1 = 0, p2 = 0, p3 = 0;
    for (int i = tid; i < Mn; i += 1024) {
        float qi = q[i];
        kq += k[i] * qi;
        qh += qi * h[i];
        p0 += qi * mu[0 * Mn + i];
        p1 += qi * mu[1 * Mn + i];
        p2 += qi * mu[2 * Mn + i];
        p3 += qi * mu[3 * Mn + i];
    }
    float rkq = blockReduce1024(kq, sred);
    float rqh = blockReduce1024(qh, sred);
    float r0 = blockReduce1024(p0, sred);
    float r1 = blockReduce1024(p1, sred);
    float r2 = blockReduce1024(p2, sred);
    float r3 = blockReduce1024(p3, sred);
    if (tid == 0) {
        const float sf = sqrtf(0.999f);
        float pu  = fmaxf(1.0f - rkq, 0.0f);      // K_xx = 1 + 1e-10 == 1.0f in fp32
        float npv = fmaxf(pu + rqh, 0.0f);
        float pv  = 0.01f + npv;
        ws[SC_PU] = pu;
        ws[SC_INVPU] = 1.0f / pu;
        ws[SC_NPV] = npv;
        ws[SC_PV] = pv;
        ws[SC_INVPV] = 1.0f / pv;
        float pm[4] = {sf * r0, sf * r1, sf * r2, sf * r3};
#pragma unroll
        for (int yd = 0; yd < 4; ++yd) {
            float yv = y[yd];
            float dy = yv - pm[yd];
            float dl = dy / pv;
            sb[yd] = dl;
            ws[OFF_MUA + yd * MUA_STRIDE + Mn] = pm[yd] + dl * npv;
            out[O_NNUM + yd] = nn[yd] + 0.999f * (dy * dy) / pv;
        }
        out[O_NDEN] = nd[0] + 0.999f;
    }
    __syncthreads();
    const float sf = sqrtf(0.999f);
    float d0 = sb[0], d1 = sb[1], d2 = sb[2], d3 = sb[3];
    for (int i = tid; i < Mn; i += 1024) {
        float hi = h[i];
        ws[OFF_MUA + 0 * MUA_STRIDE + i] = sf * mu[0 * Mn + i] + d0 * hi;
        ws[OFF_MUA + 1 * MUA_STRIDE + i] = sf * mu[1 * Mn + i] + d1 * hi;
        ws[OFF_MUA + 2 * MUA_STRIDE + i] = sf * mu[2 * Mn + i] + d2 * hi;
        ws[OFF_MUA + 3 * MUA_STRIDE + i] = sf * mu[3 * Mn + i] + d3 * hi;
    }
}

// K5: criterion rows — one block (256 thr) per row, float4 streams
__global__ __launch_bounds__(256) void k5_crit(const float* __restrict__ Q,
                                               const float* __restrict__ ti,
                                               float* __restrict__ ws) {
    __shared__ float sred[4][4];
    const int row = blockIdx.x;       // 0..Mn
    const int tid = threadIdx.x;
    const float pu = ws[SC_PU];
    if (pu < 1e-10f) {
        if (tid == 0) ws[OFF_CRIT + row] = (row < Mn) ? 1.0f : 0.0f;
        return;
    }
    const float inv_pu = ws[SC_INVPU];
    const bool rin = (row < Mn);
    const float p2i = rin ? ws[OFF_Q + row] : -1.0f;
    const float4* q4  = (const float4*)(ws + OFF_Q);
    const float4* Qr4 = (const float4*)(Q + (size_t)row * Mn);  // deref only if rin
    const float* mua = ws + OFF_MUA;
    float n0 = 0, n1 = 0, n2 = 0, n3 = 0;
#pragma unroll
    for (int it = 0; it < 4; ++it) {
        int u = tid + it * 256;
        float4 qv = q4[u];
        float4 base = rin ? Qr4[u] : make_float4(0.f, 0.f, 0.f, 0.f);
        float4 qa;
        qa.x = base.x + p2i * qv.x * inv_pu;
        qa.y = base.y + p2i * qv.y * inv_pu;
        qa.z = base.z + p2i * qv.z * inv_pu;
        qa.w = base.w + p2i * qv.w * inv_pu;
        const float4 m0 = *(const float4*)(mua + 0 * MUA_STRIDE + u * 4);
        const float4 m1 = *(const float4*)(mua + 1 * MUA_STRIDE + u * 4);
        const float4 m2 = *(const float4*)(mua + 2 * MUA_STRIDE + u * 4);
        const float4 m3 = *(const float4*)(mua + 3 * MUA_STRIDE + u * 4);
        n0 += qa.x * m0.x + qa.y * m0.y + qa.z * m0.z + qa.w * m0.w;
        n1 += qa.x * m1.x + qa.y * m1.y + qa.z * m1.z + qa.w * m1.w;
        n2 += qa.x * m2.x + qa.y * m2.y + qa.z * m2.z + qa.w * m2.w;
        n3 += qa.x * m3.x + qa.y * m3.y + qa.z * m3.z + qa.w * m3.w;
    }
    n0 = waveReduceSum(n0);
    n1 = waveReduceSum(n1);
    n2 = waveReduceSum(n2);
    n3 = waveReduceSum(n3);
    if ((tid & 63) == 0) {
        int w = tid >> 6;
        sred[w][0] = n0; sred[w][1] = n1; sred[w][2] = n2; sred[w][3] = n3;
    }
    __syncthreads();
    if (tid == 0) {
        float t0 = 0, t1 = 0, t2 = 0, t3 = 0;
#pragma unroll
        for (int w = 0; w < 4; ++w) {
            t0 += sred[w][0]; t1 += sred[w][1]; t2 += sred[w][2]; t3 += sred[w][3];
        }
        // j = Mn term: p2j = -1, base = 0
        float qaM = -p2i * inv_pu;
        t0 += qaM * mua[0 * MUA_STRIDE + Mn];
        t1 += qaM * mua[1 * MUA_STRIDE + Mn];
        t2 += qaM * mua[2 * MUA_STRIDE + Mn];
        t3 += qaM * mua[3 * MUA_STRIDE + Mn];
        bool xa = rin ? (ti[row] >= 0.0f) : true;
        float crit = 0.0f;
        if (xa) {
            float dq = rin ? (Q[(size_t)row * Mn + row] + p2i * p2i * inv_pu) : inv_pu;
            crit = fabsf(t0 / dq) + fabsf(t1 / dq) + fabsf(t2 / dq) + fabsf(t3 / dq);
        }
        ws[OFF_CRIT + row] = crit;
    }
}

// K6: argmin (first occurrence) -> prune, denom
__global__ __launch_bounds__(1024) void k6_argmin(const float* __restrict__ Q,
                                                  const float* __restrict__ ti,
                                                  float* __restrict__ ws) {
    __shared__ float sval[1024];
    __shared__ int   sidx[1024];
    const int tid = threadIdx.x;
    float bv = INFINITY;
    int bi = Mn + 1;
    for (int i = tid; i <= Mn; i += 1024) {
        float v = ws[OFF_CRIT + i];
        if (v < bv) { bv = v; bi = i; }
    }
    sval[tid] = bv; sidx[tid] = bi;
    __syncthreads();
    for (int s = 512; s > 0; s >>= 1) {
        if (tid < s) {
            float ov = sval[tid + s]; int oi = sidx[tid + s];
            if (ov < sval[tid] || (ov == sval[tid] && oi < sidx[tid])) {
                sval[tid] = ov; sidx[tid] = oi;
            }
        }
        __syncthreads();
    }
    if (tid == 0) {
        int prune = sidx[0];
        ((int*)ws)[SC_PRUNE] = prune;
        float inv_pu = ws[SC_INVPU];
        bool xa = (prune == Mn) ? true : (ti[prune] >= 0.0f);
        float qap;
        if (prune < Mn) {
            float qp = ws[OFF_Q + prune];
            qap = Q[(size_t)prune * Mn + prune] + qp * qp * inv_pu;
        } else {
            qap = inv_pu;  // Q_a[M,M] = (-1)(-1)/pu
        }
        ws[SC_DENOM] = xa ? qap : INFINITY;
    }
}

// K6b: dict_n, ti_n, Qs, Qsd
__global__ void k6b_vec(const float* __restrict__ Q, const float* __restrict__ dict,
                        const float* __restrict__ x, const float* __restrict__ ti,
                        const int* __restrict__ tptr, float* __restrict__ ws,
                        float* __restrict__ out) {
    const int tid = blockIdx.x * 256 + threadIdx.x;
    const int prune = ((const int*)ws)[SC_PRUNE];
    const int row = tid >> 6, col = tid & 63;
    out[O_DICT + tid] = (row == prune) ? x[col] : dict[tid];
    if (tid < Mn) {
        float tv = ti[tid];
        if (tid == prune) {
            int raw = *tptr;  // hedge: accept either int32 or float32-encoded t
            tv = (raw >= 0 && raw < (1 << 30)) ? (float)raw : __int_as_float(raw);
        }
        out[O_TI + tid] = tv;
        const float inv_pu = ws[SC_INVPU];
        const float denom  = ws[SC_DENOM];
        const float p2p = (prune < Mn) ? ws[OFF_Q + prune] : -1.0f;
        float qs;
        if (tid == prune) {
            qs = -p2p * inv_pu;  // Q_a[M, prune]
        } else {
            float base = (prune < Mn) ? Q[(size_t)tid * Mn + prune] : 0.0f;
            qs = base + ws[OFF_Q + tid] * p2p * inv_pu;
        }
        ws[OFF_QS + tid] = qs;
        ws[OFF_QSD + tid] = qs / denom;
    }
}

// K7: Q_n rewrite, float4 streams
__global__ void k7_qn(const float* __restrict__ Q, float* __restrict__ out,
                      const float* __restrict__ ws) {
    const int i = blockIdx.x;
    const int tid = threadIdx.x;
    const int prune = ((const int*)ws)[SC_PRUNE];
    const float inv_pu = ws[SC_INVPU];
    const int pi = (i == prune) ? Mn : i;
    const bool piok = (pi < Mn);
    const float p2i = piok ? ws[OFF_Q + pi] : -1.0f;
    const float qsi = ws[OFF_QS + i];
    const float4* Qr4  = (const float4*)(Q + (size_t)pi * Mn);   // deref only if piok
    const float4* q4   = (const float4*)(ws + OFF_Q);
    const float4* qsd4 = (const float4*)(ws + OFF_QSD);
    float4* o4 = (float4*)(out + O_Q + (size_t)i * Mn);
#pragma unroll
    for (int it = 0; it < 4; ++it) {
        int u = tid + it * 256;
        float4 base = piok ? Qr4[u] : make_float4(0.f, 0.f, 0.f, 0.f);
        float4 p2j = q4[u];
        if ((prune >> 2) == u) {     // prune < Mn lands in some u; prune==Mn never
            int c = prune & 3;
            ((float*)&p2j)[c] = -1.0f;
            ((float*)&base)[c] = 0.0f;
        }
        float4 d = qsd4[u];
        float4 r;
        r.x = base.x + p2i * p2j.x * inv_pu - qsi * d.x;
        r.y = base.y + p2i * p2j.y * inv_pu - qsi * d.y;
        r.z = base.z + p2i * p2j.z * inv_pu - qsi * d.z;
        r.w = base.w + p2i * p2j.w * inv_pu - qsi * d.w;
        o4[u] = r;
    }
}

// K8: sig_n rewrite (in-place over the sig staged in out), float4 streams
__global__ void k8_sign(float* __restrict__ out, const float* __restrict__ ws) {
    const int i = blockIdx.x;
    const int tid = threadIdx.x;
    const int prune = ((const int*)ws)[SC_PRUNE];
    const float inv_pv = ws[SC_INVPV];
    const float npv = ws[SC_NPV];
    const bool ip = (i == prune);
    const float ai = (out[O_TI + i] >= 0.0f) ? 1.0f : 0.0f;
    const float hi = ws[OFF_H + i];
    const float p_i = ip ? npv : hi;
    const float4* h4  = (const float4*)(ws + OFF_H);
    const float4* ti4 = (const float4*)(out + O_TI);
    float4* s4 = (float4*)(out + O_SIG + (size_t)i * Mn);
#pragma unroll
    for (int it = 0; it < 4; ++it) {
        int u = tid + it * 256;
        float4 sv = s4[u];
        float4 hj = h4[u];
        float4 tv = ti4[u];
        float pj[4] = {hj.x, hj.y, hj.z, hj.w};
        float bs[4];
        if (ip) { bs[0] = hj.x; bs[1] = hj.y; bs[2] = hj.z; bs[3] = hj.w; }
        else    { bs[0] = sv.x; bs[1] = sv.y; bs[2] = sv.z; bs[3] = sv.w; }
        if ((prune >> 2) == u) {
            int c = prune & 3;
            pj[c] = npv;
            bs[c] = ip ? npv : hi;
        }
        float aj[4] = {tv.x >= 0.f ? 1.f : 0.f, tv.y >= 0.f ? 1.f : 0.f,
                       tv.z >= 0.f ? 1.f : 0.f, tv.w >= 0.f ? 1.f : 0.f};
        float4 r;
        r.x = ai * aj[0] * (bs[0] - p_i * pj[0] * inv_pv);
        r.y = ai * aj[1] * (bs[1] - p_i * pj[1] * inv_pv);
        r.z = ai * aj[2] * (bs[2] - p_i * pj[2] * inv_pv);
        r.w = ai * aj[3] * (bs[3] - p_i * pj[3] * inv_pv);
        s4[u] = r;
    }
}

// K9: mu_n
__global__ void k9_mun(float* __restrict__ out, const float* __restrict__ ws) {
    const int idx = blockIdx.x * 256 + threadIdx.x;
    const int prune = ((const int*)ws)[SC_PRUNE];
    const int yd = idx >> 12;       // /4096
    const int i  = idx & (Mn - 1);
    float tin = out[O_TI + i];
    float v;
    if (tin < 0.0f) v = 0.0f;
    else v = ws[OFF_MUA + yd * MUA_STRIDE + ((i == prune) ? Mn : i)];
    out[O_MU + idx] = v;
}

extern "C" void kernel_launch(void* const* d_in, const int* in_sizes, int n_in,
                              void* d_out, int out_size, void* d_ws, size_t ws_size,
                              hipStream_t stream) {
    const float* dict  = (const float*)d_in[0];
    const float* mu    = (const float*)d_in[1];
    const float* sigma = (const float*)d_in[2];
    const float* Q     = (const float*)d_in[3];
    const float* x     = (const float*)d_in[4];
    const float* y     = (const float*)d_in[5];
    const float* nn    = (const float*)d_in[6];
    const float* nd    = (const float*)d_in[7];
    const float* ti    = (const float*)d_in[8];
    const int*   tptr  = (const int*)d_in[9];
    float* out = (float*)d_out;
    float* ws  = (float*)d_ws;

    k1_prep<<<1024, 256, 0, stream>>>(dict, x, ti, ws);
    k2_q<<<4096, 256, 0, stream>>>(Q, ws);
    k3_sig_h<<<dim3(16, 64), 256, 0, stream>>>(dict, sigma, ti, ws, out);
    k4_scalars<<<1, 1024, 0, stream>>>(mu, y, nn, nd, ws, out);
    k5_crit<<<4097, 256, 0, stream>>>(Q, ti, ws);
    k6_argmin<<<1, 1024, 0, stream>>>(Q, ti, ws);
    k6b_vec<<<1024, 256, 0, stream>>>(Q, dict, x, ti, tptr, ws, out);
    k7_qn<<<4096, 256, 0, stream>>>(Q, out, ws);
    k8_sign<<<4096, 256, 0, stream>>>(out, ws);
    k9_mun<<<64, 256, 0, stream>>>(out, ws);
}

// Round 3
// 337.568 us; speedup vs baseline: 1.2265x; 1.0227x over previous
//
#include <hip/hip_runtime.h>
#include <math.h>

#define Mn 4096
#define Dn 64
#define MUA_STRIDE 4104

// ---- workspace offsets (in floats) ----
// A2/K are dead after k4; CRIT (k5..k6) overlaps them.
#define OFF_A2   0                  /* k1..k3 */
#define OFF_CRIT 0                  /* k5..k6, 4097 floats (overlaps A2 + K[0]) */
#define OFF_K    4096               /* k1..k4 */
#define OFF_Q    8192
#define OFF_H    12288
#define OFF_MUA  16384              /* 4 x MUA_STRIDE = 16416 */
#define OFF_QS   32800
#define OFF_QSD  36896
#define SC_PU    40992
#define SC_INVPU 40993
#define SC_NPV   40994
#define SC_PV    40995
#define SC_INVPV 40996
#define SC_DENOM 40997
#define SC_PRUNE 40998              /* int slot */

// ---- output offsets (in floats) ----
#define O_MU   0
#define O_SIG  16384
#define O_Q    16793600
#define O_DICT 33570816
#define O_TI   33832960
#define O_NNUM 33837056
#define O_NDEN 33837060

__device__ __forceinline__ float waveReduceSum(float v) {
#pragma unroll
    for (int o = 32; o > 0; o >>= 1) v += __shfl_down(v, o);
    return v;
}

// K1: a2[i] = |d_i|^2 ; k[i] = exp(-max(|d_i|^2+|x|^2-2 d_i.x,0)/128) * alloc_i
__global__ void k1_prep(const float* __restrict__ dict, const float* __restrict__ x,
                        const float* __restrict__ ti, float* __restrict__ ws) {
    int row  = blockIdx.x * 4 + (threadIdx.x >> 6);
    int lane = threadIdx.x & 63;
    float d  = dict[row * Dn + lane];
    float xv = x[lane];
    float a2 = waveReduceSum(d * d);
    float x2 = waveReduceSum(xv * xv);
    float dx = waveReduceSum(d * xv);
    if (lane == 0) {
        ws[OFF_A2 + row] = a2;
        float d2 = fmaxf(a2 + x2 - 2.0f * dx, 0.0f);
        float kv = expf(d2 * (-1.0f / 128.0f));
        ws[OFF_K + row] = (ti[row] >= 0.0f) ? kv : 0.0f;
    }
}

// K2: q = Q @ k ; also zero h
__global__ void k2_q(const float* __restrict__ Q, float* __restrict__ ws) {
    __shared__ float red[4];
    const int row = blockIdx.x;
    const int tid = threadIdx.x;
    const float4* Qr = (const float4*)(Q + (size_t)row * Mn);
    const float4* kv = (const float4*)(ws + OFF_K);
    float s = 0.0f;
#pragma unroll
    for (int it = 0; it < 4; ++it) {
        int u = tid + it * 256;
        float4 a = Qr[u], b = kv[u];
        s += a.x * b.x + a.y * b.y + a.z * b.z + a.w * b.w;
    }
    s = waveReduceSum(s);
    if ((tid & 63) == 0) red[tid >> 6] = s;
    __syncthreads();
    if (tid == 0) {
        ws[OFF_Q + row] = red[0] + red[1] + red[2] + red[3];
        ws[OFF_H + row] = 0.0f;
    }
}

// K3: sig = 0.999*sigma + 0.001*Kdd(masked)  (stored into out sig region)
//     h += sig @ q   (atomic partial per 128-col chunk)
// K-major transposed LDS tiles (stride 68), register-prefetched B staging so
// the global load latency overlaps the kk loop instead of the barrier.
__global__ __launch_bounds__(256, 4) void k3_sig_h(
        const float* __restrict__ dict, const float* __restrict__ sigma,
        const float* __restrict__ ti, float* __restrict__ ws, float* __restrict__ out) {
    __shared__ __align__(16) float At[64 * 68];
    __shared__ __align__(16) float Bt[64 * 68];
    __shared__ float hred[64 * 16];
    const int tid = threadIdx.x;
    const int tx = tid & 15, ty = tid >> 4;
    const int r0 = blockIdx.y * 64;
    const int cchunk = blockIdx.x * 128;
    const int pidx = ((tid & 15) << 4) | (tid >> 4);  // permuted float4-unit id
    const int prow = pidx >> 4;                        // 0..63
    const int pcol = (pidx & 15) << 2;                 // 0..60

    // stage A (rows r0..r0+63) transposed
#pragma unroll
    for (int l = 0; l < 4; ++l) {
        int u = pidx + l * 256;          // float4 unit 0..1023
        int row = u >> 4;                // 0..63
        int col = (u & 15) << 2;         // 0..60
        float4 v = *(const float4*)(dict + (size_t)(r0 + row) * Dn + col);
        At[(col + 0) * 68 + row] = v.x;
        At[(col + 1) * 68 + row] = v.y;
        At[(col + 2) * 68 + row] = v.z;
        At[(col + 3) * 68 + row] = v.w;
    }

    float a2i[4], ali[4];
#pragma unroll
    for (int r = 0; r < 4; ++r) {
        int gi = r0 + ty * 4 + r;
        a2i[r] = ws[OFF_A2 + gi];
        ali[r] = (ti[gi] >= 0.0f) ? 1.0f : 0.0f;
    }

    float hacc[4] = {0.f, 0.f, 0.f, 0.f};

    // prefetch B tile 0 into registers
    float4 pre[4];
#pragma unroll
    for (int l = 0; l < 4; ++l) {
        int row = (pidx + l * 256) >> 4;
        int col = ((pidx + l * 256) & 15) << 2;
        pre[l] = *(const float4*)(dict + (size_t)(cchunk + row) * Dn + col);
    }

    for (int ct = 0; ct < 2; ++ct) {
        const int c0 = cchunk + ct * 64;
        __syncthreads();
#pragma unroll
        for (int l = 0; l < 4; ++l) {
            int u = pidx + l * 256;
            int row = u >> 4;
            int col = (u & 15) << 2;
            Bt[(col + 0) * 68 + row] = pre[l].x;
            Bt[(col + 1) * 68 + row] = pre[l].y;
            Bt[(col + 2) * 68 + row] = pre[l].z;
            Bt[(col + 3) * 68 + row] = pre[l].w;
        }
        if (ct < 1) {
            const int c1 = cchunk + (ct + 1) * 64;
#pragma unroll
            for (int l = 0; l < 4; ++l) {
                int row = (pidx + l * 256) >> 4;
                int col = ((pidx + l * 256) & 15) << 2;
                pre[l] = *(const float4*)(dict + (size_t)(c1 + row) * Dn + col);
            }
        }
        __syncthreads();

        float acc[4][4];
#pragma unroll
        for (int r = 0; r < 4; ++r)
#pragma unroll
            for (int c = 0; c < 4; ++c) acc[r][c] = 0.0f;

#pragma unroll
        for (int kk = 0; kk < 64; ++kk) {
            float4 av = *(const float4*)(At + kk * 68 + (ty << 2));
            float4 bv = *(const float4*)(Bt + kk * 68 + (tx << 2));
            acc[0][0] = fmaf(av.x, bv.x, acc[0][0]);
            acc[0][1] = fmaf(av.x, bv.y, acc[0][1]);
            acc[0][2] = fmaf(av.x, bv.z, acc[0][2]);
            acc[0][3] = fmaf(av.x, bv.w, acc[0][3]);
            acc[1][0] = fmaf(av.y, bv.x, acc[1][0]);
            acc[1][1] = fmaf(av.y, bv.y, acc[1][1]);
            acc[1][2] = fmaf(av.y, bv.z, acc[1][2]);
            acc[1][3] = fmaf(av.y, bv.w, acc[1][3]);
            acc[2][0] = fmaf(av.z, bv.x, acc[2][0]);
            acc[2][1] = fmaf(av.z, bv.y, acc[2][1]);
            acc[2][2] = fmaf(av.z, bv.z, acc[2][2]);
            acc[2][3] = fmaf(av.z, bv.w, acc[2][3]);
            acc[3][0] = fmaf(av.w, bv.x, acc[3][0]);
            acc[3][1] = fmaf(av.w, bv.y, acc[3][1]);
            acc[3][2] = fmaf(av.w, bv.z, acc[3][2]);
            acc[3][3] = fmaf(av.w, bv.w, acc[3][3]);
        }

        const int j = c0 + tx * 4;
        const float4 a2j4 = *(const float4*)(ws + OFF_A2 + j);
        const float4 qj4  = *(const float4*)(ws + OFF_Q + j);
        const float4 tj4  = *(const float4*)(ti + j);
        float a2j[4] = {a2j4.x, a2j4.y, a2j4.z, a2j4.w};
        float qj[4]  = {qj4.x, qj4.y, qj4.z, qj4.w};
        float alj[4] = {tj4.x >= 0.f ? 1.f : 0.f, tj4.y >= 0.f ? 1.f : 0.f,
                        tj4.z >= 0.f ? 1.f : 0.f, tj4.w >= 0.f ? 1.f : 0.f};

#pragma unroll
        for (int r = 0; r < 4; ++r) {
            const int gi = r0 + ty * 4 + r;
            const size_t off = (size_t)gi * Mn + j;
            const float4 sg = *(const float4*)(sigma + off);
            float sv[4] = {sg.x, sg.y, sg.z, sg.w};
            float res[4];
#pragma unroll
            for (int c = 0; c < 4; ++c) {
                float d2 = fmaxf(a2i[r] + a2j[c] - 2.0f * acc[r][c], 0.0f);
                float kv = __expf(d2 * (-1.0f / 128.0f)) * ali[r] * alj[c];
                res[c] = 0.999f * sv[c] + 0.001f * kv;
                hacc[r] += res[c] * qj[c];
            }
            float4 o = {res[0], res[1], res[2], res[3]};
            *(float4*)(out + O_SIG + off) = o;
        }
    }

    __syncthreads();
#pragma unroll
    for (int r = 0; r < 4; ++r) hred[(ty * 4 + r) * 16 + tx] = hacc[r];
    __syncthreads();
    if (tid < 64) {
        float s = 0.0f;
#pragma unroll
        for (int c = 0; c < 16; ++c) s += hred[tid * 16 + c];
        atomicAdd(ws + OFF_H + r0 + tid, s);
    }
}

__device__ __forceinline__ float blockReduce1024(float v, float* sred) {
    v = waveReduceSum(v);
    int tid = threadIdx.x;
    __syncthreads();
    if ((tid & 63) == 0) sred[tid >> 6] = v;
    __syncthreads();
    float r = 0.0f;
    if (tid == 0) {
#pragma unroll
        for (int i = 0; i < 16; ++i) r += sred[i];
    }
    return r;
}

// K4: scalars pu/npv/pv, pred_mean, nnum/nden, mu_a
__global__ __launch_bounds__(1024) void k4_scalars(
        const float* __restrict__ mu, const float* __restrict__ y,
        const float* __restrict__ nn, const float* __restrict__ nd,
        float* __restrict__ ws, float* __restrict__ out) {
    __shared__ float sred[16];
    __shared__ float sb[8];
    const int tid = threadIdx.x;
    const float* k = ws + OFF_K;
    const float* q = ws + OFF_Q;
    const float* h = ws + OFF_H;
    float kq = 0, qh = 0, p0 = 0, p1 = 0, p2 = 0, p3 = 0;
    for (int i = tid; i < Mn; i += 1024) {
        float qi = q[i];
        kq += k[i] * qi;
        qh += qi * h[i];
        p0 += qi * mu[0 * Mn + i];
        p1 += qi * mu[1 * Mn + i];
        p2 += qi * mu[2 * Mn + i];
        p3 += qi * mu[3 * Mn + i];
    }
    float rkq = blockReduce1024(kq, sred);
    float rqh = blockReduce1024(qh, sred);
    float r0 = blockReduce1024(p0, sred);
    float r1 = blockReduce1024(p1, sred);
    float r2 = blockReduce1024(p2, sred);
    float r3 = blockReduce1024(p3, sred);
    if (tid == 0) {
        const float sf = sqrtf(0.999f);
        float pu  = fmaxf(1.0f - rkq, 0.0f);      // K_xx = 1 + 1e-10 == 1.0f in fp32
        float npv = fmaxf(pu + rqh, 0.0f);
        float pv  = 0.01f + npv;
        ws[SC_PU] = pu;
        ws[SC_INVPU] = 1.0f / pu;
        ws[SC_NPV] = npv;
        ws[SC_PV] = pv;
        ws[SC_INVPV] = 1.0f / pv;
        float pm[4] = {sf * r0, sf * r1, sf * r2, sf * r3};
#pragma unroll
        for (int yd = 0; yd < 4; ++yd) {
            float yv = y[yd];
            float dy = yv - pm[yd];
            float dl = dy / pv;
            sb[yd] = dl;
            ws[OFF_MUA + yd * MUA_STRIDE + Mn] = pm[yd] + dl * npv;
            out[O_NNUM + yd] = nn[yd] + 0.999f * (dy * dy) / pv;
        }
        out[O_NDEN] = nd[0] + 0.999f;
    }
    __syncthreads();
    const float sf = sqrtf(0.999f);
    float d0 = sb[0], d1 = sb[1], d2 = sb[2], d3 = sb[3];
    for (int i = tid; i < Mn; i += 1024) {
        float hi = h[i];
        ws[OFF_MUA + 0 * MUA_STRIDE + i] = sf * mu[0 * Mn + i] + d0 * hi;
        ws[OFF_MUA + 1 * MUA_STRIDE + i] = sf * mu[1 * Mn + i] + d1 * hi;
        ws[OFF_MUA + 2 * MUA_STRIDE + i] = sf * mu[2 * Mn + i] + d2 * hi;
        ws[OFF_MUA + 3 * MUA_STRIDE + i] = sf * mu[3 * Mn + i] + d3 * hi;
    }
}

// K5: criterion rows — one block (256 thr) per row, float4 streams
__global__ __launch_bounds__(256) void k5_crit(const float* __restrict__ Q,
                                               const float* __restrict__ ti,
                                               float* __restrict__ ws) {
    __shared__ float sred[4][4];
    const int row = blockIdx.x;       // 0..Mn
    const int tid = threadIdx.x;
    const float pu = ws[SC_PU];
    if (pu < 1e-10f) {
        if (tid == 0) ws[OFF_CRIT + row] = (row < Mn) ? 1.0f : 0.0f;
        return;
    }
    const float inv_pu = ws[SC_INVPU];
    const bool rin = (row < Mn);
    const float p2i = rin ? ws[OFF_Q + row] : -1.0f;
    const float4* q4  = (const float4*)(ws + OFF_Q);
    const float4* Qr4 = (const float4*)(Q + (size_t)row * Mn);  // deref only if rin
    const float* mua = ws + OFF_MUA;
    float n0 = 0, n1 = 0, n2 = 0, n3 = 0;
#pragma unroll
    for (int it = 0; it < 4; ++it) {
        int u = tid + it * 256;
        float4 qv = q4[u];
        float4 base = rin ? Qr4[u] : make_float4(0.f, 0.f, 0.f, 0.f);
        float4 qa;
        qa.x = base.x + p2i * qv.x * inv_pu;
        qa.y = base.y + p2i * qv.y * inv_pu;
        qa.z = base.z + p2i * qv.z * inv_pu;
        qa.w = base.w + p2i * qv.w * inv_pu;
        const float4 m0 = *(const float4*)(mua + 0 * MUA_STRIDE + u * 4);
        const float4 m1 = *(const float4*)(mua + 1 * MUA_STRIDE + u * 4);
        const float4 m2 = *(const float4*)(mua + 2 * MUA_STRIDE + u * 4);
        const float4 m3 = *(const float4*)(mua + 3 * MUA_STRIDE + u * 4);
        n0 += qa.x * m0.x + qa.y * m0.y + qa.z * m0.z + qa.w * m0.w;
        n1 += qa.x * m1.x + qa.y * m1.y + qa.z * m1.z + qa.w * m1.w;
        n2 += qa.x * m2.x + qa.y * m2.y + qa.z * m2.z + qa.w * m2.w;
        n3 += qa.x * m3.x + qa.y * m3.y + qa.z * m3.z + qa.w * m3.w;
    }
    n0 = waveReduceSum(n0);
    n1 = waveReduceSum(n1);
    n2 = waveReduceSum(n2);
    n3 = waveReduceSum(n3);
    if ((tid & 63) == 0) {
        int w = tid >> 6;
        sred[w][0] = n0; sred[w][1] = n1; sred[w][2] = n2; sred[w][3] = n3;
    }
    __syncthreads();
    if (tid == 0) {
        float t0 = 0, t1 = 0, t2 = 0, t3 = 0;
#pragma unroll
        for (int w = 0; w < 4; ++w) {
            t0 += sred[w][0]; t1 += sred[w][1]; t2 += sred[w][2]; t3 += sred[w][3];
        }
        // j = Mn term: p2j = -1, base = 0
        float qaM = -p2i * inv_pu;
        t0 += qaM * mua[0 * MUA_STRIDE + Mn];
        t1 += qaM * mua[1 * MUA_STRIDE + Mn];
        t2 += qaM * mua[2 * MUA_STRIDE + Mn];
        t3 += qaM * mua[3 * MUA_STRIDE + Mn];
        bool xa = rin ? (ti[row] >= 0.0f) : true;
        float crit = 0.0f;
        if (xa) {
            float dq = rin ? (Q[(size_t)row * Mn + row] + p2i * p2i * inv_pu) : inv_pu;
            crit = fabsf(t0 / dq) + fabsf(t1 / dq) + fabsf(t2 / dq) + fabsf(t3 / dq);
        }
        ws[OFF_CRIT + row] = crit;
    }
}

// K6: argmin (first occurrence) -> prune, denom
__global__ __launch_bounds__(1024) void k6_argmin(const float* __restrict__ Q,
                                                  const float* __restrict__ ti,
                                                  float* __restrict__ ws) {
    __shared__ float sval[1024];
    __shared__ int   sidx[1024];
    const int tid = threadIdx.x;
    float bv = INFINITY;
    int bi = Mn + 1;
    for (int i = tid; i <= Mn; i += 1024) {
        float v = ws[OFF_CRIT + i];
        if (v < bv) { bv = v; bi = i; }
    }
    sval[tid] = bv; sidx[tid] = bi;
    __syncthreads();
    for (int s = 512; s > 0; s >>= 1) {
        if (tid < s) {
            float ov = sval[tid + s]; int oi = sidx[tid + s];
            if (ov < sval[tid] || (ov == sval[tid] && oi < sidx[tid])) {
                sval[tid] = ov; sidx[tid] = oi;
            }
        }
        __syncthreads();
    }
    if (tid == 0) {
        int prune = sidx[0];
        ((int*)ws)[SC_PRUNE] = prune;
        float inv_pu = ws[SC_INVPU];
        bool xa = (prune == Mn) ? true : (ti[prune] >= 0.0f);
        float qap;
        if (prune < Mn) {
            float qp = ws[OFF_Q + prune];
            qap = Q[(size_t)prune * Mn + prune] + qp * qp * inv_pu;
        } else {
            qap = inv_pu;  // Q_a[M,M] = (-1)(-1)/pu
        }
        ws[SC_DENOM] = xa ? qap : INFINITY;
    }
}

// K6b: dict_n, ti_n, Qs, Qsd
__global__ void k6b_vec(const float* __restrict__ Q, const float* __restrict__ dict,
                        const float* __restrict__ x, const float* __restrict__ ti,
                        const int* __restrict__ tptr, float* __restrict__ ws,
                        float* __restrict__ out) {
    const int tid = blockIdx.x * 256 + threadIdx.x;
    const int prune = ((const int*)ws)[SC_PRUNE];
    const int row = tid >> 6, col = tid & 63;
    out[O_DICT + tid] = (row == prune) ? x[col] : dict[tid];
    if (tid < Mn) {
        float tv = ti[tid];
        if (tid == prune) {
            int raw = *tptr;  // hedge: accept either int32 or float32-encoded t
            tv = (raw >= 0 && raw < (1 << 30)) ? (float)raw : __int_as_float(raw);
        }
        out[O_TI + tid] = tv;
        const float inv_pu = ws[SC_INVPU];
        const float denom  = ws[SC_DENOM];
        const float p2p = (prune < Mn) ? ws[OFF_Q + prune] : -1.0f;
        float qs;
        if (tid == prune) {
            qs = -p2p * inv_pu;  // Q_a[M, prune]
        } else {
            float base = (prune < Mn) ? Q[(size_t)tid * Mn + prune] : 0.0f;
            qs = base + ws[OFF_Q + tid] * p2p * inv_pu;
        }
        ws[OFF_QS + tid] = qs;
        ws[OFF_QSD + tid] = qs / denom;
    }
}

// K7 fused: per row i — Q_n row, sig_n row (in-place), and mu_n (4 values)
__global__ __launch_bounds__(256) void k7_fused(const float* __restrict__ Q,
                                                float* __restrict__ out,
                                                const float* __restrict__ ws) {
    const int i = blockIdx.x;
    const int tid = threadIdx.x;
    const int prune = ((const int*)ws)[SC_PRUNE];
    const float inv_pu = ws[SC_INVPU];
    const float inv_pv = ws[SC_INVPV];
    const float npv = ws[SC_NPV];

    // ---- Q_n row ----
    const int pi = (i == prune) ? Mn : i;
    const bool piok = (pi < Mn);
    const float p2i = piok ? ws[OFF_Q + pi] : -1.0f;
    const float qsi = ws[OFF_QS + i];
    const float4* Qr4  = (const float4*)(Q + (size_t)pi * Mn);   // deref only if piok
    const float4* q4   = (const float4*)(ws + OFF_Q);
    const float4* qsd4 = (const float4*)(ws + OFF_QSD);
    float4* o4 = (float4*)(out + O_Q + (size_t)i * Mn);
#pragma unroll
    for (int it = 0; it < 4; ++it) {
        int u = tid + it * 256;
        float4 base = piok ? Qr4[u] : make_float4(0.f, 0.f, 0.f, 0.f);
        float4 p2j = q4[u];
        if ((prune >> 2) == u) {     // prune < Mn lands in some u; prune==Mn never
            int c = prune & 3;
            ((float*)&p2j)[c] = -1.0f;
            ((float*)&base)[c] = 0.0f;
        }
        float4 d = qsd4[u];
        float4 r;
        r.x = base.x + p2i * p2j.x * inv_pu - qsi * d.x;
        r.y = base.y + p2i * p2j.y * inv_pu - qsi * d.y;
        r.z = base.z + p2i * p2j.z * inv_pu - qsi * d.z;
        r.w = base.w + p2i * p2j.w * inv_pu - qsi * d.w;
        o4[u] = r;
    }

    // ---- sig_n row (in place) ----
    const bool ip = (i == prune);
    const float ai = (out[O_TI + i] >= 0.0f) ? 1.0f : 0.0f;
    const float hi = ws[OFF_H + i];
    const float p_i = ip ? npv : hi;
    const float4* h4  = (const float4*)(ws + OFF_H);
    const float4* ti4 = (const float4*)(out + O_TI);
    float4* s4 = (float4*)(out + O_SIG + (size_t)i * Mn);
#pragma unroll
    for (int it = 0; it < 4; ++it) {
        int u = tid + it * 256;
        float4 sv = s4[u];
        float4 hj = h4[u];
        float4 tv = ti4[u];
        float pj[4] = {hj.x, hj.y, hj.z, hj.w};
        float bs[4];
        if (ip) { bs[0] = hj.x; bs[1] = hj.y; bs[2] = hj.z; bs[3] = hj.w; }
        else    { bs[0] = sv.x; bs[1] = sv.y; bs[2] = sv.z; bs[3] = sv.w; }
        if ((prune >> 2) == u) {
            int c = prune & 3;
            pj[c] = npv;
            bs[c] = ip ? npv : hi;
        }
        float aj[4] = {tv.x >= 0.f ? 1.f : 0.f, tv.y >= 0.f ? 1.f : 0.f,
                       tv.z >= 0.f ? 1.f : 0.f, tv.w >= 0.f ? 1.f : 0.f};
        float4 r;
        r.x = ai * aj[0] * (bs[0] - p_i * pj[0] * inv_pv);
        r.y = ai * aj[1] * (bs[1] - p_i * pj[1] * inv_pv);
        r.z = ai * aj[2] * (bs[2] - p_i * pj[2] * inv_pv);
        r.w = ai * aj[3] * (bs[3] - p_i * pj[3] * inv_pv);
        s4[u] = r;
    }

    // ---- mu_n (4 values for this row) ----
    if (tid < 4) {
        float tin = out[O_TI + i];
        float v;
        if (tin < 0.0f) v = 0.0f;
        else v = ws[OFF_MUA + tid * MUA_STRIDE + (ip ? Mn : i)];
        out[O_MU + tid * Mn + i] = v;
    }
}

extern "C" void kernel_launch(void* const* d_in, const int* in_sizes, int n_in,
                              void* d_out, int out_size, void* d_ws, size_t ws_size,
                              hipStream_t stream) {
    const float* dict  = (const float*)d_in[0];
    const float* mu    = (const float*)d_in[1];
    const float* sigma = (const float*)d_in[2];
    const float* Q     = (const float*)d_in[3];
    const float* x     = (const float*)d_in[4];
    const float* y     = (const float*)d_in[5];
    const float* nn    = (const float*)d_in[6];
    const float* nd    = (const float*)d_in[7];
    const float* ti    = (const float*)d_in[8];
    const int*   tptr  = (const int*)d_in[9];
    float* out = (float*)d_out;
    float* ws  = (float*)d_ws;

    k1_prep<<<1024, 256, 0, stream>>>(dict, x, ti, ws);
    k2_q<<<4096, 256, 0, stream>>>(Q, ws);
    k3_sig_h<<<dim3(32, 64), 256, 0, stream>>>(dict, sigma, ti, ws, out);
    k4_scalars<<<1, 1024, 0, stream>>>(mu, y, nn, nd, ws, out);
    k5_crit<<<4097, 256, 0, stream>>>(Q, ti, ws);
    k6_argmin<<<1, 1024, 0, stream>>>(Q, ti, ws);
    k6b_vec<<<1024, 256, 0, stream>>>(Q, dict, x, ti, tptr, ws, out);
    k7_fused<<<4096, 256, 0, stream>>>(Q, out, ws);
}